// Round 1
// baseline (1209.396 us; speedup 1.0000x reference)
//
#include <hip/hip_runtime.h>
#include <hip/hip_bf16.h>
#include <math.h>

// Problem constants (B=2, C=256, H=W=64, Co=256, 3x3, stride1, pad1)
#define BB 2
#define CC 256
#define HH 64
#define WW 64
#define COo 256
#define HWs 4096
#define K2 9
#define CK 2304   // C*9

// ws layout (floats)
#define O_OFF   0                       // offset buffer  B*18*4096 = 147456
#define O_MASK  147456                  // mask buffer    B*9*4096  = 73728
#define O_WT    221184                  // reg_w transposed [ck][256] = 589824
#define O_WAB   811008                  // offset/mod weights transposed [ck][32] = 73728
// total 884736 floats = 3.54 MB

// ---------------------------------------------------------------------------
// K0: pack weights. Wt[ck*256+co] = reg_w[co*2304+ck];
//     Wab[ck*32+co] = co<18 ? offset_w[co*2304+ck] : co<27 ? mod_w[(co-18)*2304+ck] : 0
// ---------------------------------------------------------------------------
__global__ __launch_bounds__(256) void pack_kernel(
    const float* __restrict__ reg_w,
    const float* __restrict__ off_w,
    const float* __restrict__ mod_w,
    float* __restrict__ Wt,
    float* __restrict__ Wab)
{
    int idx = blockIdx.x * 256 + threadIdx.x;
    if (idx < CK * COo) {
        int ck = idx >> 8;
        int co = idx & 255;
        Wt[idx] = reg_w[(size_t)co * CK + ck];
    }
    if (idx < CK * 32) {
        int ck = idx >> 5;
        int co = idx & 31;
        float v = 0.f;
        if (co < 18)      v = off_w[(size_t)co * CK + ck];
        else if (co < 27) v = mod_w[(size_t)(co - 18) * CK + ck];
        Wab[idx] = v;
    }
}

// ---------------------------------------------------------------------------
// K1: offset conv (residual -> 18ch) + modulator conv (x -> 9ch, 2*sigmoid)
// grid = B*H blocks; block 256 = (wo 64) x (cog 4); cog holds 7 output chans.
// cog0: co 0-6 (res), cog1: co 7-13 (res), cog2: co 14-20 (res+x), cog3: co 21-26 (x)
// ---------------------------------------------------------------------------
__global__ __launch_bounds__(256) void convA_kernel(
    const float* __restrict__ x,
    const float* __restrict__ residual,
    const float* __restrict__ Wab,
    const float* __restrict__ off_b,
    const float* __restrict__ mod_b,
    float* __restrict__ off_out,
    float* __restrict__ mask_out)
{
    int blk = blockIdx.x;           // b*64 + ho
    int ho = blk & 63;
    int b  = blk >> 6;
    int t  = threadIdx.x;
    int wo = t & 63;
    int cog = __builtin_amdgcn_readfirstlane(t >> 6);

    float acc[7];
#pragma unroll
    for (int j = 0; j < 7; ++j) acc[j] = 0.f;

    const float* rb = residual + (size_t)b * CC * HWs;
    const float* xb = x        + (size_t)b * CC * HWs;

    for (int c = 0; c < CC; ++c) {
        const float* rc = rb + (size_t)c * HWs;
        const float* xc = xb + (size_t)c * HWs;
#pragma unroll
        for (int ky = 0; ky < 3; ++ky) {
            int y = ho - 1 + ky;
            bool yv = (y >= 0) && (y < HH);
#pragma unroll
            for (int kx = 0; kx < 3; ++kx) {
                int xcol = wo - 1 + kx;
                bool v = yv && (xcol >= 0) && (xcol < WW);
                int lin = y * WW + xcol;
                float rv = 0.f, xv = 0.f;
                if (cog <= 2) rv = v ? rc[lin] : 0.f;
                if (cog >= 2) xv = v ? xc[lin] : 0.f;
                int ck = (c * 3 + ky) * 3 + kx;
                const float* wp = Wab + ck * 32 + cog * 7;
                if (cog < 2) {
#pragma unroll
                    for (int j = 0; j < 7; ++j) acc[j] = fmaf(rv, wp[j], acc[j]);
                } else if (cog == 2) {
#pragma unroll
                    for (int j = 0; j < 4; ++j) acc[j] = fmaf(rv, wp[j], acc[j]);
#pragma unroll
                    for (int j = 4; j < 7; ++j) acc[j] = fmaf(xv, wp[j], acc[j]);
                } else {
#pragma unroll
                    for (int j = 0; j < 6; ++j) acc[j] = fmaf(xv, wp[j], acc[j]);
                }
            }
        }
    }

#pragma unroll
    for (int j = 0; j < 7; ++j) {
        int co = cog * 7 + j;
        if (co < 18) {
            float z = acc[j] + off_b[co];
            off_out[((((size_t)b * 18 + co) * HH + ho) << 6) + wo] = z;
        } else if (co < 27) {
            float z = acc[j] + mod_b[co - 18];
            mask_out[((((size_t)b * 9 + (co - 18)) * HH + ho) << 6) + wo] =
                2.f / (1.f + expf(-z));
        }
    }
}

// ---------------------------------------------------------------------------
// K2: deformable gather + implicit GEMM.
// grid = B*H*2 blocks (co halves of 128); block 256 = (wo 64) x (cog 4).
// Per block: precompute bilinear idx/weights (mask folded) for (k,wo) into LDS,
// then 16-channel chunks: gather v tile to LDS, FMA vs scalar-loaded Wt.
// ---------------------------------------------------------------------------
__global__ __launch_bounds__(256) void deform_kernel(
    const float* __restrict__ x,
    const float* __restrict__ off,
    const float* __restrict__ mask,
    const float* __restrict__ Wt,
    float* __restrict__ out)
{
    int blk = blockIdx.x;           // ((b*64+ho)*2 + cb)
    int cb  = blk & 1;
    int ho  = (blk >> 1) & 63;
    int b   = blk >> 7;
    int t   = threadIdx.x;
    int wo  = t & 63;
    int cog = __builtin_amdgcn_readfirstlane(t >> 6);
    int co_base = cb * 128 + cog * 32;

    __shared__ int   s_idx[4 * K2 * 64];   // [corner][k][wo]
    __shared__ float s_w  [4 * K2 * 64];
    __shared__ float s_v  [16 * K2 * 64];  // [c_local][k][wo]

    // ---- precompute bilinear indices + (weight*mask) per (k, wo) ----
    for (int u = t; u < K2 * 64; u += 256) {
        int k = u >> 6;
        int w = u & 63;
        float dy = off[((((size_t)b * 18 + 2 * k    ) * HH + ho) << 6) + w];
        float dx = off[((((size_t)b * 18 + 2 * k + 1) * HH + ho) << 6) + w];
        float m  = mask[((((size_t)b * 9 + k) * HH + ho) << 6) + w];
        float py = (float)(ho - 1 + k / 3) + dy;
        float px = (float)(w  - 1 + k % 3) + dx;
        float y0f = floorf(py), x0f = floorf(px);
        float wy1 = py - y0f, wx1 = px - x0f;
        float wy0 = 1.f - wy1, wx0 = 1.f - wx1;
        int y0 = (int)y0f, x0 = (int)x0f;
#pragma unroll
        for (int j = 0; j < 4; ++j) {
            int yy = y0 + (j >> 1);
            int xx = x0 + (j & 1);
            float wj = ((j == 0) ? wy0 * wx0 :
                        (j == 1) ? wy0 * wx1 :
                        (j == 2) ? wy1 * wx0 : wy1 * wx1) * m;
            bool valid = (yy >= 0) && (yy < HH) && (xx >= 0) && (xx < WW);
            s_idx[(j * K2 + k) * 64 + w] = valid ? (yy * WW + xx) : 0;
            s_w  [(j * K2 + k) * 64 + w] = valid ? wj : 0.f;
        }
    }

    float acc[32];
#pragma unroll
    for (int i = 0; i < 32; ++i) acc[i] = 0.f;

    const float* xb = x + (size_t)b * CC * HWs;
    int cg = t >> 6;

    for (int ch = 0; ch < 16; ++ch) {
        __syncthreads();
        // ---- gather phase: 4 channels per thread ----
#pragma unroll
        for (int k = 0; k < K2; ++k) {
            int   i0 = s_idx[(0 * K2 + k) * 64 + wo];
            int   i1 = s_idx[(1 * K2 + k) * 64 + wo];
            int   i2 = s_idx[(2 * K2 + k) * 64 + wo];
            int   i3 = s_idx[(3 * K2 + k) * 64 + wo];
            float w0 = s_w [(0 * K2 + k) * 64 + wo];
            float w1 = s_w [(1 * K2 + k) * 64 + wo];
            float w2 = s_w [(2 * K2 + k) * 64 + wo];
            float w3 = s_w [(3 * K2 + k) * 64 + wo];
#pragma unroll
            for (int j = 0; j < 4; ++j) {
                int cl = cg * 4 + j;
                int c  = ch * 16 + cl;
                const float* xc = xb + (size_t)c * HWs;
                float v = w0 * xc[i0] + w1 * xc[i1] + w2 * xc[i2] + w3 * xc[i3];
                s_v[(cl * K2 + k) * 64 + wo] = v;
            }
        }
        __syncthreads();
        // ---- GEMM phase: 32 co per thread ----
#pragma unroll 4
        for (int cl = 0; cl < 16; ++cl) {
            float v9[K2];
#pragma unroll
            for (int k = 0; k < K2; ++k) v9[k] = s_v[(cl * K2 + k) * 64 + wo];
            int ckb = (ch * 16 + cl) * K2;
#pragma unroll
            for (int k = 0; k < K2; ++k) {
                const float* wp = Wt + (size_t)(ckb + k) * COo + co_base;
#pragma unroll
                for (int i = 0; i < 32; ++i)
                    acc[i] = fmaf(v9[k], wp[i], acc[i]);
            }
        }
    }

#pragma unroll
    for (int i = 0; i < 32; ++i) {
        int co = co_base + i;
        out[(((size_t)b * COo + co) * HH + ho) * WW + wo] = acc[i];
    }
}

// ---------------------------------------------------------------------------
extern "C" void kernel_launch(void* const* d_in, const int* in_sizes, int n_in,
                              void* d_out, int out_size, void* d_ws, size_t ws_size,
                              hipStream_t stream)
{
    const float* x     = (const float*)d_in[0];
    const float* resid = (const float*)d_in[1];
    const float* off_w = (const float*)d_in[2];
    const float* off_b = (const float*)d_in[3];
    const float* mod_w = (const float*)d_in[4];
    const float* mod_b = (const float*)d_in[5];
    const float* reg_w = (const float*)d_in[6];
    float* out = (float*)d_out;

    float* ws       = (float*)d_ws;
    float* off_buf  = ws + O_OFF;
    float* mask_buf = ws + O_MASK;
    float* Wt       = ws + O_WT;
    float* Wab      = ws + O_WAB;

    // K0: pack weights
    pack_kernel<<<CK * COo / 256, 256, 0, stream>>>(reg_w, off_w, mod_w, Wt, Wab);

    // K1: offset + modulator convs
    convA_kernel<<<BB * HH, 256, 0, stream>>>(x, resid, Wab, off_b, mod_b,
                                              off_buf, mask_buf);

    // K2: deformable conv main
    deform_kernel<<<BB * HH * 2, 256, 0, stream>>>(x, off_buf, mask_buf, Wt, out);
}

// Round 2
// 256.289 us; speedup vs baseline: 4.7189x; 4.7189x over previous
//
#include <hip/hip_runtime.h>
#include <hip/hip_bf16.h>
#include <math.h>

// Problem constants (B=2, C=256, H=W=64, Co=256, 3x3, stride1, pad1)
#define BB 2
#define CC 256
#define HH 64
#define WW 64
#define COo 256
#define HWs 4096
#define K2 9
#define CK 2304   // C*9

typedef __attribute__((ext_vector_type(4))) float floatx4;
typedef __attribute__((ext_vector_type(8))) short shortx8;   // 8 bf16 = 4 VGPRs

// ---- workspace layout (float units) ----
#define O_OFFR   0                        // raw offset conv (no bias): B*18*4096 = 147456 f
#define O_MASKR  147456                   // raw mod conv (no bias/sigmoid): B*9*4096 = 73728 f
#define O_WAB    221184                   // offset/mod weights [ck][32] = 73728 f
#define O_WBF    294912                   // reg_w bf16 [co][ck] = 589824 bf16 = 294912 f
#define O_A      589824                   // A matrix bf16 [pix 8192][ck 2304] = 9437184 f
// total = 10,027,008 floats = 40.1 MB

// ---------------------------------------------------------------------------
// K0: pack weights.
//   Wbf[co*2304+ck] = bf16(reg_w[co][ck])   (identical layout, cast-copy)
//   Wab[ck*32+co]   = co<18 ? off_w : co<27 ? mod_w : 0
// ---------------------------------------------------------------------------
__global__ __launch_bounds__(256) void pack_kernel(
    const float* __restrict__ reg_w,
    const float* __restrict__ off_w,
    const float* __restrict__ mod_w,
    __hip_bfloat16* __restrict__ Wbf,
    float* __restrict__ Wab)
{
    int idx = blockIdx.x * 256 + threadIdx.x;      // grid covers CK*COo = 589824
    if (idx < CK * COo) {
        Wbf[idx] = __float2bfloat16(reg_w[idx]);
    }
    if (idx < CK * 32) {
        int ck = idx >> 5;
        int co = idx & 31;
        float v = 0.f;
        if (co < 18)      v = off_w[(size_t)co * CK + ck];
        else if (co < 27) v = mod_w[(size_t)(co - 18) * CK + ck];
        Wab[idx] = v;
    }
}

// ---------------------------------------------------------------------------
// K1: offset conv (residual -> 18ch) + modulator conv (x -> 9ch), RAW outputs
// (bias & sigmoid applied later). K-split over input channels: grid =
// B*H*8 blocks, each block does 32 input channels, atomicAdd partials.
// block 256 = (wo 64) x (cog 4); cog holds 7 output chans.
// ---------------------------------------------------------------------------
__global__ __launch_bounds__(256) void convA_kernel(
    const float* __restrict__ x,
    const float* __restrict__ residual,
    const float* __restrict__ Wab,
    float* __restrict__ off_raw,
    float* __restrict__ mask_raw)
{
    int blk = blockIdx.x;            // ((b*64 + ho)*8 + cc)
    int cc = blk & 7;
    int ho = (blk >> 3) & 63;
    int b  = blk >> 9;
    int t  = threadIdx.x;
    int wo = t & 63;
    int cog = __builtin_amdgcn_readfirstlane(t >> 6);

    float acc[7];
#pragma unroll
    for (int j = 0; j < 7; ++j) acc[j] = 0.f;

    const float* rb = residual + ((size_t)b * CC + cc * 32) * HWs;
    const float* xb = x        + ((size_t)b * CC + cc * 32) * HWs;

    for (int c = 0; c < 32; ++c) {
        const float* rc = rb + (size_t)c * HWs;
        const float* xc = xb + (size_t)c * HWs;
        int cglob = cc * 32 + c;
#pragma unroll
        for (int ky = 0; ky < 3; ++ky) {
            int y = ho - 1 + ky;
            bool yv = (y >= 0) && (y < HH);
#pragma unroll
            for (int kx = 0; kx < 3; ++kx) {
                int xcol = wo - 1 + kx;
                bool v = yv && (xcol >= 0) && (xcol < WW);
                int lin = y * WW + xcol;
                float rv = 0.f, xv = 0.f;
                if (cog <= 2) rv = v ? rc[lin] : 0.f;
                if (cog >= 2) xv = v ? xc[lin] : 0.f;
                int ck = (cglob * 3 + ky) * 3 + kx;
                const float* wp = Wab + ck * 32 + cog * 7;
                if (cog < 2) {
#pragma unroll
                    for (int j = 0; j < 7; ++j) acc[j] = fmaf(rv, wp[j], acc[j]);
                } else if (cog == 2) {
#pragma unroll
                    for (int j = 0; j < 4; ++j) acc[j] = fmaf(rv, wp[j], acc[j]);
#pragma unroll
                    for (int j = 4; j < 7; ++j) acc[j] = fmaf(xv, wp[j], acc[j]);
                } else {
#pragma unroll
                    for (int j = 0; j < 6; ++j) acc[j] = fmaf(xv, wp[j], acc[j]);
                }
            }
        }
    }

#pragma unroll
    for (int j = 0; j < 7; ++j) {
        int co = cog * 7 + j;
        if (co < 18) {
            atomicAdd(&off_raw[((((size_t)b * 18 + co) * HH + ho) << 6) + wo], acc[j]);
        } else if (co < 27) {
            atomicAdd(&mask_raw[((((size_t)b * 9 + (co - 18)) * HH + ho) << 6) + wo], acc[j]);
        }
    }
}

// ---------------------------------------------------------------------------
// K2: deformable gather -> bf16 A matrix [pix][ck], coalesced via LDS.
// grid = B*H*8 (c-chunk of 32); block 256 = (wo 64) x (cg 4), 8 chan each.
// ---------------------------------------------------------------------------
__global__ __launch_bounds__(256) void gather_kernel(
    const float* __restrict__ x,
    const float* __restrict__ off_raw,
    const float* __restrict__ mask_raw,
    const float* __restrict__ off_b,
    const float* __restrict__ mod_b,
    __hip_bfloat16* __restrict__ A)
{
    int blk = blockIdx.x;            // ((b*64 + ho)*8 + cc)
    int cc = blk & 7;
    int ho = (blk >> 3) & 63;
    int b  = blk >> 9;
    int t  = threadIdx.x;
    int wo = t & 63;
    int cg = t >> 6;

    __shared__ int   s_idx[4][K2][64];
    __shared__ float s_w  [4][K2][64];
    __shared__ __hip_bfloat16 s_a[64][288];   // [wo][ck_local]

    // ---- bilinear sample precompute (bias + sigmoid applied here) ----
    for (int u = t; u < K2 * 64; u += 256) {
        int k = u >> 6;
        int w = u & 63;
        float dy = off_raw[((((size_t)b * 18 + 2 * k    ) * HH + ho) << 6) + w] + off_b[2 * k];
        float dx = off_raw[((((size_t)b * 18 + 2 * k + 1) * HH + ho) << 6) + w] + off_b[2 * k + 1];
        float z  = mask_raw[((((size_t)b * 9 + k) * HH + ho) << 6) + w] + mod_b[k];
        float m  = 2.f / (1.f + __expf(-z));
        float py = (float)(ho - 1 + k / 3) + dy;
        float px = (float)(w  - 1 + k % 3) + dx;
        float y0f = floorf(py), x0f = floorf(px);
        float wy1 = py - y0f, wx1 = px - x0f;
        float wy0 = 1.f - wy1, wx0 = 1.f - wx1;
        int y0 = (int)y0f, x0 = (int)x0f;
#pragma unroll
        for (int j = 0; j < 4; ++j) {
            int yy = y0 + (j >> 1);
            int xx = x0 + (j & 1);
            float wj = ((j == 0) ? wy0 * wx0 :
                        (j == 1) ? wy0 * wx1 :
                        (j == 2) ? wy1 * wx0 : wy1 * wx1) * m;
            bool valid = (yy >= 0) && (yy < HH) && (xx >= 0) && (xx < WW);
            s_idx[j][k][w] = valid ? (yy * WW + xx) : 0;
            s_w  [j][k][w] = valid ? wj : 0.f;
        }
    }
    __syncthreads();

    // ---- gather 8 channels per thread ----
    const float* xb = x + ((size_t)b * CC + cc * 32) * HWs;
#pragma unroll
    for (int j = 0; j < 8; ++j) {
        int cl = cg * 8 + j;                   // 0..31
        const float* xc = xb + (size_t)cl * HWs;
#pragma unroll
        for (int k = 0; k < K2; ++k) {
            int   i0 = s_idx[0][k][wo], i1 = s_idx[1][k][wo];
            int   i2 = s_idx[2][k][wo], i3 = s_idx[3][k][wo];
            float w0 = s_w[0][k][wo], w1 = s_w[1][k][wo];
            float w2 = s_w[2][k][wo], w3 = s_w[3][k][wo];
            float v = w0 * xc[i0] + w1 * xc[i1] + w2 * xc[i2] + w3 * xc[i3];
            s_a[wo][cl * 9 + k] = __float2bfloat16(v);
        }
    }
    __syncthreads();

    // ---- coalesced write-out: 64 rows x 576 B = 2304 chunks of 16B ----
    int pixbase = (b * 64 + ho) * 64;
#pragma unroll
    for (int it = 0; it < 9; ++it) {
        int id = it * 256 + t;                 // 0..2303
        int r  = id / 36;
        int ch = id % 36;
        shortx8 v = *(const shortx8*)&s_a[r][ch * 8];
        *(shortx8*)(A + (size_t)(pixbase + r) * CK + cc * 288 + ch * 8) = v;
    }
}

// ---------------------------------------------------------------------------
// K3: bf16 MFMA GEMM  C[8192][256] = A[8192][2304] x W^T, out in NCHW.
// grid = 64 Mtiles x 4 Ntiles = 256 blocks; tile 128M x 64N, BK=32.
// block 256 = 4 waves, each wave 32M x 64N (2x4 16x16 frags).
// ---------------------------------------------------------------------------
#define BKp 40   // padded LDS K-pitch (elements): kills b128 bank conflicts
__global__ __launch_bounds__(256) void gemm_kernel(
    const __hip_bfloat16* __restrict__ A,
    const __hip_bfloat16* __restrict__ Wbf,
    float* __restrict__ out)
{
    int blk = blockIdx.x;
    int mt = blk >> 2;          // 0..63 : pix base mt*128 (one b, contiguous hw)
    int nt = blk & 3;           // co base nt*64
    int t  = threadIdx.x;
    int lane = t & 63;
    int w    = t >> 6;
    int quad = lane >> 4;
    int ln   = lane & 15;

    __shared__ __hip_bfloat16 As[128 * BKp];   // [row][k] pitch 40
    __shared__ __hip_bfloat16 Bs[64 * BKp];
    __shared__ float s_out[16 * 132];          // epilogue transpose

    // staging addresses: A chunks id = {t, 256+t}: row=id>>2, kc=id&3
    int arow0 = t >> 2, akc = t & 3;
    const __hip_bfloat16* gA0 = A + (size_t)(mt * 128 + arow0) * CK + akc * 8;
    const __hip_bfloat16* gA1 = gA0 + (size_t)64 * CK;
    int brow = t >> 2;
    const __hip_bfloat16* gB = Wbf + (size_t)(nt * 64 + brow) * CK + akc * 8;

    floatx4 acc[2][4];
#pragma unroll
    for (int mi = 0; mi < 2; ++mi)
#pragma unroll
        for (int ns = 0; ns < 4; ++ns) acc[mi][ns] = (floatx4){0.f, 0.f, 0.f, 0.f};

    shortx8 ra0 = *(const shortx8*)gA0;
    shortx8 ra1 = *(const shortx8*)gA1;
    shortx8 rb0 = *(const shortx8*)gB;

    for (int kt = 0; kt < 72; ++kt) {
        __syncthreads();
        *(shortx8*)&As[arow0 * BKp + akc * 8] = ra0;
        *(shortx8*)&As[(arow0 + 64) * BKp + akc * 8] = ra1;
        *(shortx8*)&Bs[brow * BKp + akc * 8] = rb0;
        __syncthreads();
        if (kt + 1 < 72) {
            int ko = (kt + 1) * 32;
            ra0 = *(const shortx8*)(gA0 + ko);
            ra1 = *(const shortx8*)(gA1 + ko);
            rb0 = *(const shortx8*)(gB + ko);
        }
        shortx8 a0 = *(const shortx8*)&As[(w * 32 + ln) * BKp + quad * 8];
        shortx8 a1 = *(const shortx8*)&As[(w * 32 + 16 + ln) * BKp + quad * 8];
#pragma unroll
        for (int ns = 0; ns < 4; ++ns) {
            shortx8 bfr = *(const shortx8*)&Bs[(ns * 16 + ln) * BKp + quad * 8];
            acc[0][ns] = __builtin_amdgcn_mfma_f32_16x16x32_bf16(a0, bfr, acc[0][ns], 0, 0, 0);
            acc[1][ns] = __builtin_amdgcn_mfma_f32_16x16x32_bf16(a1, bfr, acc[1][ns], 0, 0, 0);
        }
    }

    // ---- epilogue: transpose through LDS, coalesced NCHW stores ----
    int bb = mt >> 5;                   // batch
    int hwbase = (mt & 31) * 128;       // 128 contiguous hw pixels
#pragma unroll
    for (int ns = 0; ns < 4; ++ns) {
        __syncthreads();
#pragma unroll
        for (int mi = 0; mi < 2; ++mi) {
            floatx4 v = acc[mi][ns];
            *(floatx4*)&s_out[ln * 132 + w * 32 + mi * 16 + quad * 4] = v;
        }
        __syncthreads();
#pragma unroll
        for (int it = 0; it < 2; ++it) {
            int id = it * 256 + t;          // 0..511
            int co_l = id >> 5;             // 0..15
            int mch  = id & 31;             // 0..31 (4 floats each)
            floatx4 v = *(const floatx4*)&s_out[co_l * 132 + mch * 4];
            int co = nt * 64 + ns * 16 + co_l;
            *(floatx4*)&out[((size_t)(bb * COo + co) << 12) + hwbase + mch * 4] = v;
        }
    }
}

// ---------------------------------------------------------------------------
extern "C" void kernel_launch(void* const* d_in, const int* in_sizes, int n_in,
                              void* d_out, int out_size, void* d_ws, size_t ws_size,
                              hipStream_t stream)
{
    const float* x     = (const float*)d_in[0];
    const float* resid = (const float*)d_in[1];
    const float* off_w = (const float*)d_in[2];
    const float* off_b = (const float*)d_in[3];
    const float* mod_w = (const float*)d_in[4];
    const float* mod_b = (const float*)d_in[5];
    const float* reg_w = (const float*)d_in[6];
    float* out = (float*)d_out;

    float* ws        = (float*)d_ws;
    float* off_raw   = ws + O_OFFR;
    float* mask_raw  = ws + O_MASKR;
    float* Wab       = ws + O_WAB;
    __hip_bfloat16* Wbf = (__hip_bfloat16*)(ws + O_WBF);
    __hip_bfloat16* Abuf = (__hip_bfloat16*)(ws + O_A);

    // zero the atomic accumulators (ws is poisoned before every launch)
    hipMemsetAsync(off_raw, 0, (147456 + 73728) * sizeof(float), stream);

    pack_kernel<<<(CK * COo + 255) / 256, 256, 0, stream>>>(reg_w, off_w, mod_w, Wbf, Wab);

    convA_kernel<<<BB * HH * 8, 256, 0, stream>>>(x, resid, Wab, off_raw, mask_raw);

    gather_kernel<<<BB * HH * 8, 256, 0, stream>>>(x, off_raw, mask_raw,
                                                   off_b, mod_b, Abuf);

    gemm_kernel<<<64 * 4, 256, 0, stream>>>(Abuf, Wbf, out);
}

// Round 3
// 235.518 us; speedup vs baseline: 5.1350x; 1.0882x over previous
//
#include <hip/hip_runtime.h>
#include <hip/hip_bf16.h>
#include <math.h>

// Problem constants (B=2, C=256, H=W=64, Co=256, 3x3, stride1, pad1)
#define BB 2
#define CC 256
#define HH 64
#define WW 64
#define COo 256
#define HWs 4096
#define K2 9
#define CK 2304   // C*9

typedef __attribute__((ext_vector_type(4))) float floatx4;
typedef __attribute__((ext_vector_type(8))) short shortx8;   // 8 bf16 = 4 VGPRs

// ---- workspace layout (float units) ----
#define O_OFF   0          // final offset (bias applied)  B*18*4096 = 147456 f
#define O_MASK  147456     // final modulator (sigmoid'd)  B*9*4096  =  73728 f
#define O_WBF   221184     // reg_w bf16 [co][ck] = 589824 bf16 = 294912 f
#define O_WPK   516096     // convA weights, MFMA-frag order = 147456 bf16 = 73728 f
#define O_A     589824     // A matrix bf16 [pix 8192][ck 2304] = 9437184 f
// total = 10,027,008 floats = 40.1 MB

__device__ __forceinline__ void gll16(const __hip_bfloat16* g, __hip_bfloat16* l) {
    __builtin_amdgcn_global_load_lds(
        (const __attribute__((address_space(1))) unsigned int*)g,
        (__attribute__((address_space(3))) unsigned int*)l, 16, 0, 0);
}

__device__ __forceinline__ short f2bf(float v) {
    __hip_bfloat16 h = __float2bfloat16(v);
    return *reinterpret_cast<short*>(&h);
}

// ---------------------------------------------------------------------------
// K0: pack weights.
//  Wbf[co*2304+ck] = bf16(reg_w) (cast-copy, natural layout)
//  Wpk: convA weights in MFMA B-frag order:
//   [g 2][tap 9][kchunk 8][nfrag 2][lane 64][j 8],
//   c = kchunk*32 + (lane>>4)*8 + j, n = nfrag*16 + (lane&15)
//   g=0: n<18 -> off_w[n][c][tap]; g=1: n<9 -> mod_w[n][c][tap]; else 0
// ---------------------------------------------------------------------------
__global__ __launch_bounds__(256) void pack_kernel(
    const float* __restrict__ reg_w,
    const float* __restrict__ off_w,
    const float* __restrict__ mod_w,
    __hip_bfloat16* __restrict__ Wbf,
    __hip_bfloat16* __restrict__ Wpk)
{
    int idx = blockIdx.x * 256 + threadIdx.x;      // grid covers CK*COo = 589824
    if (idx < CK * COo) {
        Wbf[idx] = __float2bfloat16(reg_w[idx]);
    }
    if (idx < 147456) {
        int g    = idx / 73728;
        int rem  = idx % 73728;
        int tap  = rem / 8192;
        int rem2 = rem % 8192;
        int kc   = rem2 >> 10;
        int nf   = (rem2 >> 9) & 1;
        int lane = (rem2 >> 3) & 63;
        int j    = rem2 & 7;
        int c    = kc * 32 + (lane >> 4) * 8 + j;
        int n    = nf * 16 + (lane & 15);
        float v = 0.f;
        if (g == 0) { if (n < 18) v = off_w[((size_t)n * CC + c) * 9 + tap]; }
        else        { if (n < 9)  v = mod_w[((size_t)n * CC + c) * 9 + tap]; }
        Wpk[idx] = __float2bfloat16(v);
    }
}

// ---------------------------------------------------------------------------
// K1: offset + modulator convs via MFMA.
// grid = 256: blk = ((b*2+g)*64 + r). g=0: input residual -> 18 offset ch;
// g=1: input x -> 9 mod ch (2*sigmoid fused). Block = 4 waves; wave w owns
// pixels w*16..w*16+15 of row r; N=32 (2 nfrags).
// LDS: 3 rows x 64 cols x 64 ch bf16, XOR-swizzled c-chunks (conflict-free).
// ---------------------------------------------------------------------------
__global__ __launch_bounds__(256) void convA_kernel(
    const float* __restrict__ x,
    const float* __restrict__ residual,
    const __hip_bfloat16* __restrict__ Wpk,
    const float* __restrict__ off_b,
    const float* __restrict__ mod_b,
    float* __restrict__ off_out,
    float* __restrict__ mask_out)
{
    int blk = blockIdx.x;
    int r = blk & 63;
    int g = (blk >> 6) & 1;
    int b = blk >> 7;
    int t = threadIdx.x;
    int lane = t & 63;
    int w = t >> 6;
    int ln = lane & 15;
    int quad = lane >> 4;

    __shared__ __hip_bfloat16 Ls[3 * 64 * 64];   // [colIdx = row*64+col][c 64], swizzled

    const float* src = (g ? x : residual) + (size_t)b * CC * HWs;
    const __hip_bfloat16* wbase = Wpk + (size_t)g * 73728;

    floatx4 acc[2];
    acc[0] = (floatx4){0.f, 0.f, 0.f, 0.f};
    acc[1] = (floatx4){0.f, 0.f, 0.f, 0.f};

    int col = t & 63;
    int q = t >> 6;

    for (int st = 0; st < 4; ++st) {       // 64-channel stagings
        __syncthreads();
        // stage: 24 (row,cgroup) pairs, 6 per 64-thread group; 8 coalesced
        // channel-lines each, packed to one swizzled ds_write_b128.
#pragma unroll
        for (int i = 0; i < 6; ++i) {
            int p = q * 6 + i;             // 0..23
            int row = p >> 3;              // 0..2
            int cgp = p & 7;               // c-chunk of 8
            int rimg = r + row - 1;
            bool rv = (rimg >= 0) && (rimg < HH);
            const float* sp = src + (size_t)(st * 64 + cgp * 8) * HWs + rimg * WW + col;
            shortx8 pk;
#pragma unroll
            for (int jc = 0; jc < 8; ++jc)
                pk[jc] = f2bf(rv ? sp[(size_t)jc * HWs] : 0.f);
            int colIdx = row * 64 + col;
            int pos = cgp ^ (colIdx & 7);
            *(shortx8*)&Ls[colIdx * 64 + pos * 8] = pk;
        }
        __syncthreads();
        // compute: 9 taps x 2 k-halves x 2 nfrags
#pragma unroll
        for (int tap = 0; tap < 9; ++tap) {
            int ky = tap / 3;
            int kx = tap % 3;
            int colA = w * 16 + ln + kx - 1;
            bool cv = (colA >= 0) && (colA < WW);
            int colC = cv ? colA : 0;
            int colIdx = ky * 64 + colC;
#pragma unroll
            for (int kh = 0; kh < 2; ++kh) {
                int chunk = kh * 4 + quad;
                int pos = chunk ^ (colIdx & 7);
                shortx8 afr = *(const shortx8*)&Ls[colIdx * 64 + pos * 8];
                if (!cv) {
                    shortx8 zf = {0,0,0,0,0,0,0,0};
                    afr = zf;
                }
                int kc = st * 2 + kh;
                const __hip_bfloat16* wp = wbase + (((size_t)(tap * 8 + kc) * 2) * 64 + lane) * 8;
                shortx8 b0 = *(const shortx8*)wp;
                shortx8 b1 = *(const shortx8*)(wp + 512);
                acc[0] = __builtin_amdgcn_mfma_f32_16x16x32_bf16(afr, b0, acc[0], 0, 0, 0);
                acc[1] = __builtin_amdgcn_mfma_f32_16x16x32_bf16(afr, b1, acc[1], 0, 0, 0);
            }
        }
    }

    // epilogue: C/D layout col=lane&15 (=n), row=quad*4+reg (=pixel)
#pragma unroll
    for (int nf = 0; nf < 2; ++nf) {
        int n = nf * 16 + ln;
#pragma unroll
        for (int i2 = 0; i2 < 4; ++i2) {
            int pix = w * 16 + quad * 4 + i2;
            float v = acc[nf][i2];
            if (g == 0) {
                if (n < 18)
                    off_out[(((size_t)b * 18 + n) * HH + r) * WW + pix] = v + off_b[n];
            } else {
                if (n < 9) {
                    float z = v + mod_b[n];
                    mask_out[(((size_t)b * 9 + n) * HH + r) * WW + pix] =
                        2.f / (1.f + __expf(-z));
                }
            }
        }
    }
}

// ---------------------------------------------------------------------------
// K2: deformable gather -> bf16 A matrix [pix][ck], coalesced via LDS.
// grid = B*H*8 (c-chunk of 32); block 256 = (wo 64) x (cg 4), 8 chan each.
// k-outer loop: 8 LDS idx/w reads per k shared across 8 channels.
// ---------------------------------------------------------------------------
__global__ __launch_bounds__(256) void gather_kernel(
    const float* __restrict__ x,
    const float* __restrict__ off,
    const float* __restrict__ mask,
    __hip_bfloat16* __restrict__ A)
{
    int blk = blockIdx.x;            // ((b*64 + ho)*8 + cc)
    int cc = blk & 7;
    int ho = (blk >> 3) & 63;
    int b  = blk >> 9;
    int t  = threadIdx.x;
    int wo = t & 63;
    int cg = t >> 6;

    __shared__ int   s_idx[4][K2][64];
    __shared__ float s_w  [4][K2][64];
    __shared__ __hip_bfloat16 s_a[64][288];   // [wo][ck_local]

    // ---- bilinear sample precompute (offset/mask are final values) ----
    for (int u = t; u < K2 * 64; u += 256) {
        int k = u >> 6;
        int wv = u & 63;
        float dy = off[((((size_t)b * 18 + 2 * k    ) * HH + ho) << 6) + wv];
        float dx = off[((((size_t)b * 18 + 2 * k + 1) * HH + ho) << 6) + wv];
        float m  = mask[((((size_t)b * 9 + k) * HH + ho) << 6) + wv];
        float py = (float)(ho - 1 + k / 3) + dy;
        float px = (float)(wv - 1 + k % 3) + dx;
        float y0f = floorf(py), x0f = floorf(px);
        float wy1 = py - y0f, wx1 = px - x0f;
        float wy0 = 1.f - wy1, wx0 = 1.f - wx1;
        int y0 = (int)y0f, x0 = (int)x0f;
#pragma unroll
        for (int j = 0; j < 4; ++j) {
            int yy = y0 + (j >> 1);
            int xx = x0 + (j & 1);
            float wj = ((j == 0) ? wy0 * wx0 :
                        (j == 1) ? wy0 * wx1 :
                        (j == 2) ? wy1 * wx0 : wy1 * wx1) * m;
            bool valid = (yy >= 0) && (yy < HH) && (xx >= 0) && (xx < WW);
            s_idx[j][k][wv] = valid ? (yy * WW + xx) : 0;
            s_w  [j][k][wv] = valid ? wj : 0.f;
        }
    }
    __syncthreads();

    // ---- gather: k-outer, 8 channels inner ----
    const float* xb = x + ((size_t)b * CC + cc * 32) * HWs;
#pragma unroll
    for (int k = 0; k < K2; ++k) {
        int   i0 = s_idx[0][k][wo], i1 = s_idx[1][k][wo];
        int   i2 = s_idx[2][k][wo], i3 = s_idx[3][k][wo];
        float w0 = s_w[0][k][wo], w1 = s_w[1][k][wo];
        float w2 = s_w[2][k][wo], w3 = s_w[3][k][wo];
#pragma unroll
        for (int j = 0; j < 8; ++j) {
            int cl = cg * 8 + j;
            const float* xc = xb + (size_t)cl * HWs;
            float v = w0 * xc[i0] + w1 * xc[i1] + w2 * xc[i2] + w3 * xc[i3];
            s_a[wo][cl * 9 + k] = __float2bfloat16(v);
        }
    }
    __syncthreads();

    // ---- coalesced write-out: 64 rows x 576 B = 2304 chunks of 16B ----
    int pixbase = (b * 64 + ho) * 64;
#pragma unroll
    for (int it = 0; it < 9; ++it) {
        int id = it * 256 + t;                 // 0..2303
        int rr = id / 36;
        int ch = id % 36;
        shortx8 v = *(const shortx8*)&s_a[rr][ch * 8];
        *(shortx8*)(A + (size_t)(pixbase + rr) * CK + cc * 288 + ch * 8) = v;
    }
}

// ---------------------------------------------------------------------------
// K3: bf16 MFMA GEMM  C[8192][256] = A[8192][2304] x Wbf^T, out NCHW.
// grid = 64 Mtiles x 4 Ntiles; tile 128M x 64N, BK=32.
// Staging via global_load_lds (16B) with XOR k-chunk swizzle applied to the
// GLOBAL source address; LDS reads land conflict-free (uniform 32-bank cover).
// ---------------------------------------------------------------------------
__global__ __launch_bounds__(256) void gemm_kernel(
    const __hip_bfloat16* __restrict__ A,
    const __hip_bfloat16* __restrict__ Wbf,
    float* __restrict__ out)
{
    int blk = blockIdx.x;
    int mt = blk >> 2;          // pix base mt*128
    int nt = blk & 3;           // co base nt*64
    int t  = threadIdx.x;
    int lane = t & 63;
    int w    = t >> 6;
    int quad = lane >> 4;
    int ln   = lane & 15;

    __shared__ __hip_bfloat16 As[128 * 32];   // 8 KB, [row][swizzled k-chunk]
    __shared__ __hip_bfloat16 Bs[64 * 32];    // 4 KB
    __shared__ float s_out[16 * 132];         // epilogue transpose

    int lr  = lane >> 2;                      // 0..15
    int swz = (lane & 3) ^ (lr & 3);          // global k-chunk this lane fetches
    const __hip_bfloat16* gA0 = A + (size_t)(mt * 128 + w * 32 + lr) * CK + swz * 8;
    const __hip_bfloat16* gA1 = gA0 + (size_t)16 * CK;
    const __hip_bfloat16* gB  = Wbf + (size_t)(nt * 64 + w * 16 + lr) * CK + swz * 8;
    __hip_bfloat16* lA0 = &As[(w * 32) * 32];
    __hip_bfloat16* lA1 = &As[(w * 32 + 16) * 32];
    __hip_bfloat16* lB  = &Bs[(w * 16) * 32];

    floatx4 acc[2][4];
#pragma unroll
    for (int mi = 0; mi < 2; ++mi)
#pragma unroll
        for (int ns = 0; ns < 4; ++ns) acc[mi][ns] = (floatx4){0.f, 0.f, 0.f, 0.f};

    int sA = quad ^ (ln & 3);                 // swizzled read chunk

    for (int kt = 0; kt < 72; ++kt) {
        __syncthreads();
        gll16(gA0 + kt * 32, lA0);
        gll16(gA1 + kt * 32, lA1);
        gll16(gB  + kt * 32, lB);
        __syncthreads();
        shortx8 a0 = *(const shortx8*)&As[(w * 32 + ln) * 32 + sA * 8];
        shortx8 a1 = *(const shortx8*)&As[(w * 32 + 16 + ln) * 32 + sA * 8];
#pragma unroll
        for (int ns = 0; ns < 4; ++ns) {
            shortx8 bfr = *(const shortx8*)&Bs[(ns * 16 + ln) * 32 + sA * 8];
            acc[0][ns] = __builtin_amdgcn_mfma_f32_16x16x32_bf16(a0, bfr, acc[0][ns], 0, 0, 0);
            acc[1][ns] = __builtin_amdgcn_mfma_f32_16x16x32_bf16(a1, bfr, acc[1][ns], 0, 0, 0);
        }
    }

    // ---- epilogue: transpose through LDS, coalesced NCHW stores ----
    int bb = mt >> 5;                   // batch
    int hwbase = (mt & 31) * 128;       // 128 contiguous hw pixels
#pragma unroll
    for (int ns = 0; ns < 4; ++ns) {
        __syncthreads();
#pragma unroll
        for (int mi = 0; mi < 2; ++mi) {
            floatx4 v = acc[mi][ns];
            *(floatx4*)&s_out[ln * 132 + w * 32 + mi * 16 + quad * 4] = v;
        }
        __syncthreads();
#pragma unroll
        for (int it = 0; it < 2; ++it) {
            int id = it * 256 + t;          // 0..511
            int co_l = id >> 5;             // 0..15
            int mch  = id & 31;             // 0..31 (4 floats each)
            floatx4 v = *(const floatx4*)&s_out[co_l * 132 + mch * 4];
            int co = nt * 64 + ns * 16 + co_l;
            *(floatx4*)&out[((size_t)(bb * COo + co) << 12) + hwbase + mch * 4] = v;
        }
    }
}

// ---------------------------------------------------------------------------
extern "C" void kernel_launch(void* const* d_in, const int* in_sizes, int n_in,
                              void* d_out, int out_size, void* d_ws, size_t ws_size,
                              hipStream_t stream)
{
    const float* x     = (const float*)d_in[0];
    const float* resid = (const float*)d_in[1];
    const float* off_w = (const float*)d_in[2];
    const float* off_b = (const float*)d_in[3];
    const float* mod_w = (const float*)d_in[4];
    const float* mod_b = (const float*)d_in[5];
    const float* reg_w = (const float*)d_in[6];
    float* out = (float*)d_out;

    float* ws        = (float*)d_ws;
    float* off_buf   = ws + O_OFF;
    float* mask_buf  = ws + O_MASK;
    __hip_bfloat16* Wbf  = (__hip_bfloat16*)(ws + O_WBF);
    __hip_bfloat16* Wpk  = (__hip_bfloat16*)(ws + O_WPK);
    __hip_bfloat16* Abuf = (__hip_bfloat16*)(ws + O_A);

    pack_kernel<<<(CK * COo + 255) / 256, 256, 0, stream>>>(reg_w, off_w, mod_w, Wbf, Wpk);

    convA_kernel<<<BB * 2 * HH, 256, 0, stream>>>(x, resid, Wpk, off_b, mod_b,
                                                  off_buf, mask_buf);

    gather_kernel<<<BB * HH * 8, 256, 0, stream>>>(x, off_buf, mask_buf, Abuf);

    gemm_kernel<<<64 * 4, 256, 0, stream>>>(Abuf, Wbf, out);
}